// Round 9
// baseline (53.684 us; speedup 1.0000x reference)
//
#include <hip/hip_runtime.h>

// DQSN forward, fully fused (v6): closed-form spike period + arithmetic A
// (zero main-loop DS) + LDS-transpose epilogue (DS-pipe de-bottlenecked).
//
// out[b,o] = sum_h W2[o,h] * A[b,h] + b2[o] * (1 - 2^-16)
// A depends only on n = first j in 1..16 with fp32-cumsum_j(I) >= 1
// (hard reset to exactly 0.0 -> exactly periodic spike train, period n).
//
// n = med3(ceil(rcp(I)), 1, 17); provably equal to the fp32-cumsum crossing
// outside a |r - nearest-int| < GUARD band (rcp err ~2e-6, cumsum shift
// <= 1.6e-5); in-band waves take the exact 16-step sim, corrected via
// acc += (A_exact - A_opt)*w2.
//
// A is computed ARITHMETICALLY (no table, no bpermute):
//   m(n) = sum_{k: kn<=16} 2^(kn-1);  bits of m at kn-1 <-> bits at 16-kn
//   => floor(65535/(2^n-1)) = bitreverse16(m(n))
//   => A*2^32 = (float)bitreverse32( (uint)(65535*rcp(2^n-1) + 0.5) )
// Exact for n in [1,17] (worst margin n=17: 0.49999 + 0.5 + 6e-8 < 1).
// The 2^32 scale is removed once at the end (exact power-of-2 scaling).

constexpr int TSTEPS = 16;
constexpr int NB = 8;                 // batch rows per block (grid = 2048)
constexpr float GUARD = 4e-5f;
constexpr float GTHR  = 0.5f - GUARD;

__device__ __forceinline__ float A_scaled(float nf) {
    // nf integer-valued in [1,17]; returns m(n) * 2^16 exactly (0 for n=17).
    const int   ni = (int)nf;
    const float p  = __builtin_amdgcn_ldexpf(1.0f, ni);   // 2^n
    const float q  = p - 1.0f;                            // 2^n - 1 (exact)
    const float t  = __builtin_amdgcn_rcpf(q);
    const float u  = fmaf(t, 65535.0f, 0.5f);
    const unsigned qu = (unsigned)u;                      // floor(65535/q)
    return (float)__builtin_bitreverse32(qu);             // m<<16, low bits 0
}

template <int CITERS>
__global__ __launch_bounds__(256) void dqsn_fwd(
    const float* __restrict__ x,
    const float* __restrict__ W1,
    const float* __restrict__ b1,
    const float* __restrict__ W2,
    const float* __restrict__ b2,
    float* __restrict__ out,
    int B, int H, int iters_rt)
{
    const int tid = threadIdx.x;
    const int b0  = blockIdx.x * NB;

    // x rows for this block: block-uniform -> scalar loads / SGPRs
    float xs0[NB], xs1[NB], xs2[NB], xs3[NB];
#pragma unroll
    for (int i = 0; i < NB; ++i) {
        const int bi = (b0 + i < B) ? (b0 + i) : (B - 1);
        xs0[i] = x[bi * 4 + 0];
        xs1[i] = x[bi * 4 + 1];
        xs2[i] = x[bi * 4 + 2];
        xs3[i] = x[bi * 4 + 3];
    }

    float acc0[NB], acc1[NB];   // scaled by 2^32 until the epilogue
#pragma unroll
    for (int i = 0; i < NB; ++i) { acc0[i] = 0.0f; acc1[i] = 0.0f; }

    const int iters = (CITERS > 0) ? CITERS : iters_rt;

#pragma unroll 4
    for (int it = 0; it < iters; ++it) {
        const int h = tid + (it << 8);
        const float4 w1 = *reinterpret_cast<const float4*>(W1 + (size_t)h * 4);
        const float bb  = b1[h];
        const float w2a = W2[h];
        const float w2b = W2[H + h];

        float I[NB], As[NB];
        float emax = 0.0f;
#pragma unroll
        for (int i = 0; i < NB; ++i) {
            I[i] = fmaf(xs0[i], w1.x,
                   fmaf(xs1[i], w1.y,
                   fmaf(xs2[i], w1.z,
                   fmaf(xs3[i], w1.w, bb))));
            const float r = __builtin_amdgcn_rcpf(I[i]);
            const float c = __builtin_ceilf(r);
            const float nf = __builtin_amdgcn_fmed3f(c, 1.0f, 17.0f);
            float A = A_scaled(nf);
            As[i] = (c > 0.0f) ? A : 0.0f;        // I<=0 -> no spikes
            emax = fmaxf(emax, fabsf((r - c) + 0.5f)); // ~0.5 <=> breakpoint
        }

#pragma unroll
        for (int i = 0; i < NB; ++i) {
            acc0[i] = fmaf(As[i], w2a, acc0[i]);
            acc1[i] = fmaf(As[i], w2b, acc1[i]);
        }

        // rare corrective patch-up: exact 16-step sim, add the delta
        if (__builtin_expect((unsigned long long)__ballot(emax > GTHR), 0)) {
#pragma unroll
            for (int i = 0; i < NB; ++i) {
                float v = 0.0f;
                int cnt = 0;
#pragma unroll
                for (int t = 0; t < TSTEPS; ++t) {
                    v += I[i];
                    cnt += (v < 1.0f) ? 1 : 0;
                }
                const float An = A_scaled((float)(cnt + 1)); // n in [1,17]
                const float dA = An - As[i];   // exactly 0.0 if unaffected
                acc0[i] = fmaf(dA, w2a, acc0[i]);
                acc1[i] = fmaf(dA, w2b, acc1[i]);
            }
        }
    }

    // ---- epilogue: LDS-transpose reduction (DS-light) ----
    // layout: row per thread, 16 values, stride 20 floats (bank-spread, 16B-aligned)
    __shared__ float lds[256 * 20];
    __shared__ float lds2[256];

    {
        float* base = &lds[tid * 20];
        *reinterpret_cast<float4*>(base +  0) = (float4){acc0[0], acc1[0], acc0[1], acc1[1]};
        *reinterpret_cast<float4*>(base +  4) = (float4){acc0[2], acc1[2], acc0[3], acc1[3]};
        *reinterpret_cast<float4*>(base +  8) = (float4){acc0[4], acc1[4], acc0[5], acc1[5]};
        *reinterpret_cast<float4*>(base + 12) = (float4){acc0[6], acc1[6], acc0[7], acc1[7]};
    }
    __syncthreads();

    // summer (o = output slot 0..15, j = 0..15) sums 16 interleaved rows
    {
        const int o = tid & 15;
        const int j = tid >> 4;
        float s = 0.0f;
#pragma unroll
        for (int k = 0; k < 16; ++k)
            s += lds[(j + 16 * k) * 20 + o];
        lds2[tid] = s;
    }
    __syncthreads();

    if (tid < 16) {
        float tot = 0.0f;
#pragma unroll
        for (int j = 0; j < 16; ++j)
            tot += lds2[j * 16 + tid];
        const int i  = tid >> 1;
        const int oo = tid & 1;
        if (b0 + i < B)
            out[(b0 + i) * 2 + oo] =
                fmaf(tot, 0x1p-32f, b2[oo] * (1.0f - 0x1p-16f));
    }
}

extern "C" void kernel_launch(void* const* d_in, const int* in_sizes, int n_in,
                              void* d_out, int out_size, void* d_ws, size_t ws_size,
                              hipStream_t stream) {
    const float* x  = (const float*)d_in[0];
    const float* W1 = (const float*)d_in[1];
    const float* b1 = (const float*)d_in[2];
    const float* W2 = (const float*)d_in[3];
    const float* b2 = (const float*)d_in[4];
    float* out = (float*)d_out;

    const int B = in_sizes[0] / 4;   // 16384
    const int H = in_sizes[2];       // 4096

    const int grid = (B + NB - 1) / NB;
    if (H == 4096) {
        dqsn_fwd<16><<<grid, 256, 0, stream>>>(x, W1, b1, W2, b2, out, B, H, 16);
    } else {
        dqsn_fwd<0><<<grid, 256, 0, stream>>>(x, W1, b1, W2, b2, out, B, H, H / 256);
    }
}

// Round 10
// 38.233 us; speedup vs baseline: 1.4041x; 1.4041x over previous
//
#include <hip/hip_runtime.h>

// DQSN forward, fully fused (v7): closed-form spike period + bpermute table
// (R6 structure) + v_pk_fma_f32 packing + value-halving shuffle epilogue.
//
// out[b,o] = sum_h W2[o,h] * A[b,h] + b2[o] * (1 - 2^-16)
// A depends only on n = first j in 1..16 with fp32-cumsum_j(I) >= 1
// (hard reset to exactly 0.0 -> exactly periodic spike train, period n).
// n = med3(ceil(rcp(I)), 0, 17); provably equals the fp32-cumsum crossing
// outside the |r - nearest-int| < GUARD band; in-band waves (P ~ 1e-4) are
// patched with the exact 16-step simulation via acc += (A_exact - A_opt)*w2.

typedef float v2f __attribute__((ext_vector_type(2)));

constexpr int TSTEPS = 16;
constexpr int NB = 8;                  // batch rows per block (grid = 2048)
constexpr int NP = NB / 2;
constexpr float GUARD = 4e-5f;
constexpr float GTHR  = 0.5f - GUARD;

template <int CITERS>
__global__ __launch_bounds__(256, 8) void dqsn_fwd(
    const float* __restrict__ x,
    const float* __restrict__ W1,
    const float* __restrict__ b1,
    const float* __restrict__ W2,
    const float* __restrict__ b2,
    float* __restrict__ out,
    int B, int H, int iters_rt)
{
    const int tid  = threadIdx.x;
    const int lane = tid & 63;
    const int b0   = blockIdx.x * NB;

    // per-lane A(n) table: lane l (1..16) holds A for period n=l.
    // lanes 0 and 17+ hold 0.0 (n=0: I<=0; n=17: no spike within 16 steps).
    float tval = 0.0f;
    if (lane >= 1 && lane <= TSTEPS) {
        unsigned mm = 0;
        for (int k = lane; k <= TSTEPS; k += lane) mm |= 1u << (k - 1);
        tval = (float)mm * 0x1p-16f;   // exact: mm < 2^17
    }
    const int table_reg = __float_as_int(tval);

    // x rows packed as (row 2ip, row 2ip+1) pairs for v_pk_fma_f32
    v2f xp0[NP], xp1[NP], xp2[NP], xp3[NP];
#pragma unroll
    for (int ip = 0; ip < NP; ++ip) {
        int ra = b0 + 2 * ip, rb = b0 + 2 * ip + 1;
        ra = (ra < B) ? ra : B - 1;
        rb = (rb < B) ? rb : B - 1;
        xp0[ip] = (v2f){x[ra * 4 + 0], x[rb * 4 + 0]};
        xp1[ip] = (v2f){x[ra * 4 + 1], x[rb * 4 + 1]};
        xp2[ip] = (v2f){x[ra * 4 + 2], x[rb * 4 + 2]};
        xp3[ip] = (v2f){x[ra * 4 + 3], x[rb * 4 + 3]};
    }

    v2f acc0[NP], acc1[NP];   // acc0[ip] = out0 partials for rows (2ip, 2ip+1)
#pragma unroll
    for (int ip = 0; ip < NP; ++ip) {
        acc0[ip] = (v2f){0.0f, 0.0f};
        acc1[ip] = (v2f){0.0f, 0.0f};
    }

    const int iters = (CITERS > 0) ? CITERS : iters_rt;

#pragma unroll
    for (int it = 0; it < iters; ++it) {
        const int h = tid + (it << 8);
        const float4 w1 = *reinterpret_cast<const float4*>(W1 + (size_t)h * 4);
        const float bb  = b1[h];
        const float w2a = W2[h];
        const float w2b = W2[H + h];

        // I for all NB rows, two at a time (v_pk_fma_f32, splat via op_sel)
        v2f I2[NP], Ap[NP];
        float emax = 0.0f;
#pragma unroll
        for (int ip = 0; ip < NP; ++ip) {
            v2f t  = __builtin_elementwise_fma(xp3[ip], (v2f){w1.w, w1.w}, (v2f){bb, bb});
            t      = __builtin_elementwise_fma(xp2[ip], (v2f){w1.z, w1.z}, t);
            t      = __builtin_elementwise_fma(xp1[ip], (v2f){w1.y, w1.y}, t);
            I2[ip] = __builtin_elementwise_fma(xp0[ip], (v2f){w1.x, w1.x}, t);
        }

#pragma unroll
        for (int ip = 0; ip < NP; ++ip) {
            {
                const float r = __builtin_amdgcn_rcpf(I2[ip].x);
                const float c = __builtin_ceilf(r);
                const int idx = (int)__builtin_amdgcn_fmed3f(c, 0.0f, 17.0f) << 2;
                emax = fmaxf(emax, fabsf((r - c) + 0.5f));
                Ap[ip].x = __int_as_float(__builtin_amdgcn_ds_bpermute(idx, table_reg));
            }
            {
                const float r = __builtin_amdgcn_rcpf(I2[ip].y);
                const float c = __builtin_ceilf(r);
                const int idx = (int)__builtin_amdgcn_fmed3f(c, 0.0f, 17.0f) << 2;
                emax = fmaxf(emax, fabsf((r - c) + 0.5f));
                Ap[ip].y = __int_as_float(__builtin_amdgcn_ds_bpermute(idx, table_reg));
            }
        }

#pragma unroll
        for (int ip = 0; ip < NP; ++ip) {
            acc0[ip] = __builtin_elementwise_fma(Ap[ip], (v2f){w2a, w2a}, acc0[ip]);
            acc1[ip] = __builtin_elementwise_fma(Ap[ip], (v2f){w2b, w2b}, acc1[ip]);
        }

        // rare corrective patch-up: exact 16-step sim, add the delta
        if (__builtin_expect((unsigned long long)__ballot(emax > GTHR), 0)) {
#pragma unroll
            for (int ip = 0; ip < NP; ++ip) {
#pragma unroll
                for (int u = 0; u < 2; ++u) {
                    const float I = u ? I2[ip].y : I2[ip].x;
                    float v = 0.0f;
                    int cnt = 0;
#pragma unroll
                    for (int t = 0; t < TSTEPS; ++t) {
                        v += I;
                        cnt += (v < 1.0f) ? 1 : 0;
                    }
                    const float An = __int_as_float(
                        __builtin_amdgcn_ds_bpermute((cnt + 1) << 2, table_reg));
                    const float Ao = u ? Ap[ip].y : Ap[ip].x;
                    const float dA = An - Ao;        // exactly 0.0 if unaffected
                    if (u) {
                        acc0[ip].y = fmaf(dA, w2a, acc0[ip].y);
                        acc1[ip].y = fmaf(dA, w2b, acc1[ip].y);
                    } else {
                        acc0[ip].x = fmaf(dA, w2a, acc0[ip].x);
                        acc1[ip].x = fmaf(dA, w2b, acc1[ip].x);
                    }
                }
            }
        }
    }

    // ---- epilogue: value-halving wave reduction (17 DS vs 96) ----
    // v[j], j = 2*row_local + o
    float v[16];
#pragma unroll
    for (int ip = 0; ip < NP; ++ip) {
        v[4 * ip + 0] = acc0[ip].x;   // row 2ip,   out0
        v[4 * ip + 1] = acc1[ip].x;   // row 2ip,   out1
        v[4 * ip + 2] = acc0[ip].y;   // row 2ip+1, out0
        v[4 * ip + 3] = acc1[ip].y;   // row 2ip+1, out1
    }

    {   // off=32: 16 -> 8 values
        const bool up = (lane & 32) != 0;
#pragma unroll
        for (int k = 0; k < 8; ++k) {
            const float mine = up ? v[k] : v[k + 8];
            const float recv = __shfl_xor(mine, 32, 64);
            v[k] = (up ? v[k + 8] : v[k]) + recv;
        }
    }
    {   // off=16: 8 -> 4
        const bool up = (lane & 16) != 0;
#pragma unroll
        for (int k = 0; k < 4; ++k) {
            const float mine = up ? v[k] : v[k + 4];
            const float recv = __shfl_xor(mine, 16, 64);
            v[k] = (up ? v[k + 4] : v[k]) + recv;
        }
    }
    {   // off=8: 4 -> 2
        const bool up = (lane & 8) != 0;
#pragma unroll
        for (int k = 0; k < 2; ++k) {
            const float mine = up ? v[k] : v[k + 2];
            const float recv = __shfl_xor(mine, 8, 64);
            v[k] = (up ? v[k + 2] : v[k]) + recv;
        }
    }
    {   // off=4: 2 -> 1; value index = (lane>>2)&15
        const bool up = (lane & 4) != 0;
        const float mine = up ? v[0] : v[1];
        const float recv = __shfl_xor(mine, 4, 64);
        v[0] = (up ? v[1] : v[0]) + recv;
    }
    float tot = v[0];
    tot += __shfl_xor(tot, 1, 64);
    tot += __shfl_xor(tot, 2, 64);

    __shared__ float red[4][16];
    if ((lane & 3) == 0) red[tid >> 6][lane >> 2] = tot;
    __syncthreads();

    if (tid < 16) {
        const float s = (red[0][tid] + red[1][tid]) + (red[2][tid] + red[3][tid]);
        const int i = tid >> 1;
        const int o = tid & 1;
        if (b0 + i < B)
            out[(b0 + i) * 2 + o] = s + b2[o] * (1.0f - 0x1p-16f);
    }
}

extern "C" void kernel_launch(void* const* d_in, const int* in_sizes, int n_in,
                              void* d_out, int out_size, void* d_ws, size_t ws_size,
                              hipStream_t stream) {
    const float* x  = (const float*)d_in[0];
    const float* W1 = (const float*)d_in[1];
    const float* b1 = (const float*)d_in[2];
    const float* W2 = (const float*)d_in[3];
    const float* b2 = (const float*)d_in[4];
    float* out = (float*)d_out;

    const int B = in_sizes[0] / 4;   // 16384
    const int H = in_sizes[2];       // 4096

    const int grid = (B + NB - 1) / NB;
    if (H == 4096) {
        dqsn_fwd<16><<<grid, 256, 0, stream>>>(x, W1, b1, W2, b2, out, B, H, 16);
    } else {
        dqsn_fwd<0><<<grid, 256, 0, stream>>>(x, W1, b1, W2, b2, out, B, H, H / 256);
    }
}